// Round 5
// baseline (294.874 us; speedup 1.0000x reference)
//
#include <hip/hip_runtime.h>
#include <hip/hip_bf16.h>
#include <cstdint>
#include <cstddef>

// JacobiKANLinear: DEGREE=5, A=B=1.0
#define BATCH   8192
#define IN_F    1024
#define OUT_F   1024
#define KAUG    (6 * 1024)   // slab 0 = silu(x); slab j (1..5) = P_j(tanh x); P0 folded into bias

typedef __bf16 bf16x8 __attribute__((ext_vector_type(8)));
typedef float  f32x4  __attribute__((ext_vector_type(4)));

// Big-workspace layout (fast path, needs ~113.3 MB):
static constexpr size_t WAUG_B    = (size_t)OUT_F * KAUG * 2;        // 12,582,912
static constexpr size_t BIAS2_OFF = WAUG_B;                          // 4 KB f32
static constexpr size_t AAUG_OFF  = WAUG_B + 4096;
static constexpr size_t AAUG_B    = (size_t)BATCH * KAUG * 2;        // 100,663,296
static constexpr size_t FLAGS_OFF = AAUG_OFF + AAUG_B;
static constexpr size_t MMAP_OFF  = FLAGS_OFF + 64;
static constexpr size_t NMAP_OFF  = MMAP_OFF + 1024;
static constexpr size_t NEEDED_BIG = NMAP_OFF + 1024;
// Small-workspace layout (direct path, needs 8 KB):
static constexpr size_t S_FLAGS = 0, S_MMAP = 128, S_NMAP = 1152, S_BIAS2 = 4096;

// Jacobi recurrence for A=B=1 (beta_n = 0): P_k = (a_k t)P_{k-1} - (b_k)P_{k-2}
__device__ __constant__ float JAC_A[4] = {64.f/120.f, 180.f/336.f, 384.f/720.f, 700.f/1320.f};
__device__ __constant__ float JAC_B[4] = {48.f/120.f, 144.f/336.f, 320.f/720.f, 600.f/1320.f};

// ---------------- dtype detection (per input; 1 = fp32, 0 = bf16) ----------------
__global__ void detect_dtype(const void* p0, const void* p1,
                             const void* p2, const void* p3,
                             int* __restrict__ flags)
{
    const void* ps[4] = {p0, p1, p2, p3};
    const __hip_bfloat16* b = (const __hip_bfloat16*)ps[blockIdx.x];
    const float v = __bfloat162float(b[threadIdx.x]);
    const bool bad = (!(v == v)) || (fabsf(v) > 1000.f);
    const unsigned long long m = __ballot(bad);
    __shared__ int s[4];
    if ((threadIdx.x & 63) == 0) s[threadIdx.x >> 6] = (m != 0ull) ? 1 : 0;
    __syncthreads();
    if (threadIdx.x == 0) flags[blockIdx.x] = s[0] | s[1] | s[2] | s[3];
}

__device__ __forceinline__ float load_in(const void* p, size_t idx, int isf32)
{
    if (isf32) return ((const float*)p)[idx];
    const unsigned short u = ((const unsigned short*)p)[idx];
    return __uint_as_float((unsigned)u << 16);
}

__device__ __forceinline__ float4 load4(const void* p, size_t idx, int isf32)
{
    if (isf32) return *(const float4*)((const float*)p + idx);
    const ushort4 u = *(const ushort4*)((const unsigned short*)p + idx);
    float4 r;
    r.x = __uint_as_float((unsigned)u.x << 16);
    r.y = __uint_as_float((unsigned)u.y << 16);
    r.z = __uint_as_float((unsigned)u.z << 16);
    r.w = __uint_as_float((unsigned)u.w << 16);
    return r;
}

__device__ __forceinline__ unsigned short f2bf(float f)
{
    __hip_bfloat16 h = __float2bfloat16(f);
    return *(unsigned short*)&h;
}

__device__ __forceinline__ float slabf(float xv, int j)
{
    if (j == 0) return xv / (1.f + __expf(-xv));        // silu
    const float xc = fminf(fmaxf(xv, -15.f), 15.f);
    const float e  = __expf(2.f * xc);
    const float t  = (e - 1.f) / (e + 1.f);
    float pm2 = 1.f, pm1 = 2.f * t;                     // P1 = 2t
    if (j == 1) return pm1;
    float pk = pm1;
#pragma unroll
    for (int k = 2; k <= 5; ++k) {
        if (k > j) break;
        pk = JAC_A[k - 2] * t * pm1 - JAC_B[k - 2] * pm2;
        pm2 = pm1; pm1 = pk;
    }
    return pk;
}

// ---------------- MFMA C/D layout probe ----------------
__global__ void probe_layout(int* __restrict__ mmap, int* __restrict__ nmap)
{
    __shared__ __align__(16) __hip_bfloat16 A1[16 * 32], B1[16 * 32];
    __shared__ __align__(16) __hip_bfloat16 A2[16 * 32], B2[16 * 32];
    const int lane = threadIdx.x;
    for (int e = lane; e < 512; e += 64) {
        const int m = e >> 5, k = e & 31;
        A1[e] = __float2bfloat16((k == 0) ? (float)(m + 1) : 0.f);
        B1[e] = __float2bfloat16((k == 0) ? 1.f : 0.f);
        A2[e] = __float2bfloat16((k == 0) ? 1.f : 0.f);
        B2[e] = __float2bfloat16((k == 0) ? (float)(m + 1) : 0.f);
    }
    __syncthreads();
    const int quad = lane >> 4, mr = lane & 15;
    const int fi = mr * 4 + quad;
    const bf16x8* A1v = (const bf16x8*)A1;
    const bf16x8* B1v = (const bf16x8*)B1;
    const bf16x8* A2v = (const bf16x8*)A2;
    const bf16x8* B2v = (const bf16x8*)B2;
    f32x4 z = {};
    f32x4 d1 = __builtin_amdgcn_mfma_f32_16x16x32_bf16(A1v[fi], B1v[fi], z, 0, 0, 0);
    f32x4 d2 = __builtin_amdgcn_mfma_f32_16x16x32_bf16(A2v[fi], B2v[fi], z, 0, 0, 0);
#pragma unroll
    for (int r = 0; r < 4; ++r) {
        mmap[lane * 4 + r] = (int)(d1[r] + 0.5f) - 1;
        nmap[lane * 4 + r] = (int)(d2[r] + 0.5f) - 1;
    }
}

// ---------------- bias fold: bias2[o] = bias[o] + sum_i C[o][i][0] ----------------
__global__ void prep_bias(const void* __restrict__ C,
                          const void* __restrict__ bias,
                          float* __restrict__ bias2,
                          const int* __restrict__ flags)
{
    const int fC = flags[2], fB = flags[3];
    const int o = blockIdx.x;
    float s = 0.f;
    for (int i = threadIdx.x; i < IN_F; i += 256)
        s += load_in(C, ((size_t)o * IN_F + i) * 6, fC);
#pragma unroll
    for (int off = 32; off > 0; off >>= 1)
        s += __shfl_down(s, off, 64);
    __shared__ float red[4];
    if ((threadIdx.x & 63) == 0) red[threadIdx.x >> 6] = s;
    __syncthreads();
    if (threadIdx.x == 0)
        bias2[o] = load_in(bias, o, fB) + red[0] + red[1] + red[2] + red[3];
}

// ---------------- fast-path prep ----------------
__global__ void prep_weights(const void* __restrict__ W,
                             const void* __restrict__ C,
                             __hip_bfloat16* __restrict__ Waug,
                             const int* __restrict__ flags)
{
    const int fW = flags[1], fC = flags[2];
    const int idx = blockIdx.x * 256 + threadIdx.x;
    const int o = idx >> 10;
    const int i = idx & (IN_F - 1);
    const size_t wbase = (size_t)o * KAUG;
    Waug[wbase + i] = __float2bfloat16(load_in(W, idx, fW));
    const size_t cbase = (size_t)idx * 6;
#pragma unroll
    for (int j = 1; j <= 5; ++j)
        Waug[wbase + (size_t)j * IN_F + i] = __float2bfloat16(load_in(C, cbase + j, fC));
}

__global__ void prep_acts(const void* __restrict__ X,
                          __hip_bfloat16* __restrict__ Aaug,
                          const int* __restrict__ flags)
{
    const int fX = flags[0];
    const int idx = blockIdx.x * 256 + threadIdx.x;
    const int b = idx >> 10;
    const int i = idx & (IN_F - 1);
    const float xf = load_in(X, idx, fX);
    const size_t base = (size_t)b * KAUG;
    Aaug[base + i] = __float2bfloat16(xf / (1.f + __expf(-xf)));
    const float t = tanhf(xf);
    float pm2 = 1.f, pm1 = 2.f * t;
    Aaug[base + IN_F + i] = __float2bfloat16(pm1);
#pragma unroll
    for (int k = 2; k <= 5; ++k) {
        const float pk = JAC_A[k - 2] * t * pm1 - JAC_B[k - 2] * pm2;
        Aaug[base + (size_t)k * IN_F + i] = __float2bfloat16(pk);
        pm2 = pm1; pm1 = pk;
    }
}

// ---------------- shared epilogue helper ----------------
__device__ __forceinline__ void write_epilogue(
    f32x4 (&acc)[4][4], const int* mmap, const int* nmap,
    int lane, int wm, int wn, int mBase, int nBase,
    const float* bias2, float* out)
{
    const int4 mv = ((const int4*)mmap)[lane];
    const int4 nv = ((const int4*)nmap)[lane];
    const int mm[4] = {mv.x, mv.y, mv.z, mv.w};
    const int nn[4] = {nv.x, nv.y, nv.z, nv.w};
#pragma unroll
    for (int i = 0; i < 4; ++i) {
#pragma unroll
        for (int jj = 0; jj < 4; ++jj) {
#pragma unroll
            for (int r = 0; r < 4; ++r) {
                const int row = mBase + wm * 64 + i * 16 + mm[r];
                const int col = nBase + wn * 64 + jj * 16 + nn[r];
                out[(size_t)row * OUT_F + col] = acc[i][jj][r] + bias2[col];  // fp32 OUT
            }
        }
    }
}

// ---------------- fast GEMM (prep'd Aaug/Waug, explicit LDS staging) ----------------
__global__ __launch_bounds__(256, 2)
void gemm_kan(const __hip_bfloat16* __restrict__ Aaug,
              const __hip_bfloat16* __restrict__ Waug,
              const float* __restrict__ bias2,
              const int* __restrict__ mmap,
              const int* __restrict__ nmap,
              float* __restrict__ out)
{
    __shared__ __align__(16) __hip_bfloat16 As[128 * 32];
    __shared__ __align__(16) __hip_bfloat16 Bs[128 * 32];

    const int tid  = threadIdx.x;
    const int lane = tid & 63;
    const int wave = tid >> 6;
    const int wm = wave & 1, wn = wave >> 1;
    const int mBase = blockIdx.y * 128;
    const int nBase = blockIdx.x * 128;

    const int srow = tid >> 2;              // 0..63
    const int scol = (tid & 3) * 8;         // 0,8,16,24
    const __hip_bfloat16* gA0 = Aaug + (size_t)(mBase + srow) * KAUG + scol;
    const __hip_bfloat16* gA1 = gA0 + (size_t)64 * KAUG;
    const __hip_bfloat16* gB0 = Waug + (size_t)(nBase + srow) * KAUG + scol;
    const __hip_bfloat16* gB1 = gB0 + (size_t)64 * KAUG;
    uint4* const dA0 = (uint4*)&As[srow * 32 + scol];
    uint4* const dA1 = (uint4*)&As[(64 + srow) * 32 + scol];
    uint4* const dB0 = (uint4*)&Bs[srow * 32 + scol];
    uint4* const dB1 = (uint4*)&Bs[(64 + srow) * 32 + scol];

    f32x4 acc[4][4] = {};
    const int quad = lane >> 4, mr = lane & 15;

    for (int k0 = 0; k0 < KAUG; k0 += 32) {
        const uint4 ra0 = *(const uint4*)(gA0 + k0);
        const uint4 ra1 = *(const uint4*)(gA1 + k0);
        const uint4 rb0 = *(const uint4*)(gB0 + k0);
        const uint4 rb1 = *(const uint4*)(gB1 + k0);
        __syncthreads();
        *dA0 = ra0; *dA1 = ra1; *dB0 = rb0; *dB1 = rb1;
        __syncthreads();

        const bf16x8* AsV = (const bf16x8*)As;
        const bf16x8* BsV = (const bf16x8*)Bs;
        bf16x8 a[4], b[4];
#pragma unroll
        for (int t = 0; t < 4; ++t) a[t] = AsV[(wm * 64 + t * 16 + mr) * 4 + quad];
#pragma unroll
        for (int t = 0; t < 4; ++t) b[t] = BsV[(wn * 64 + t * 16 + mr) * 4 + quad];
#pragma unroll
        for (int i = 0; i < 4; ++i)
#pragma unroll
            for (int jj = 0; jj < 4; ++jj)
                acc[i][jj] = __builtin_amdgcn_mfma_f32_16x16x32_bf16(a[i], b[jj], acc[i][jj], 0, 0, 0);
    }
    write_epilogue(acc, mmap, nmap, lane, wm, wn, mBase, nBase, bias2, out);
}

// ---------------- direct GEMM (no big workspace; on-the-fly slabs) ----------------
__global__ __launch_bounds__(256, 2)
void gemm_direct(const void* __restrict__ x,
                 const void* __restrict__ W,
                 const void* __restrict__ C,
                 const float* __restrict__ bias2,
                 const int* __restrict__ flags,
                 const int* __restrict__ mmap,
                 const int* __restrict__ nmap,
                 float* __restrict__ out)
{
    __shared__ __align__(16) __hip_bfloat16 As[128 * 32];
    __shared__ __align__(16) __hip_bfloat16 Bs[128 * 32];

    const int tid  = threadIdx.x;
    const int lane = tid & 63;
    const int wave = tid >> 6;
    const int wm = wave & 1, wn = wave >> 1;
    const int mBase = blockIdx.y * 128;
    const int nBase = blockIdx.x * 128;
    const int fX = flags[0], fW = flags[1], fC = flags[2];

    const int srow = tid >> 3;              // 0..31
    const int scol = (tid & 7) * 4;         // 0,4,...,28

    f32x4 acc[4][4] = {};
    const int quad = lane >> 4, mr = lane & 15;

    for (int k0 = 0; k0 < KAUG; k0 += 32) {
        const int j  = k0 >> 10;
        const int i0 = k0 & (IN_F - 1);
        ushort4 aval[4], bval[4];
#pragma unroll
        for (int rr = 0; rr < 4; ++rr) {
            const int row = srow + rr * 32;
            const float4 xv = load4(x, (size_t)(mBase + row) * IN_F + i0 + scol, fX);
            aval[rr].x = f2bf(slabf(xv.x, j));
            aval[rr].y = f2bf(slabf(xv.y, j));
            aval[rr].z = f2bf(slabf(xv.z, j));
            aval[rr].w = f2bf(slabf(xv.w, j));
            float4 wv;
            if (j == 0) {
                wv = load4(W, (size_t)(nBase + row) * IN_F + i0 + scol, fW);
            } else {
                const size_t cb = ((size_t)(nBase + row) * IN_F + i0 + scol) * 6 + j;
                wv.x = load_in(C, cb,      fC);
                wv.y = load_in(C, cb + 6,  fC);
                wv.z = load_in(C, cb + 12, fC);
                wv.w = load_in(C, cb + 18, fC);
            }
            bval[rr].x = f2bf(wv.x);
            bval[rr].y = f2bf(wv.y);
            bval[rr].z = f2bf(wv.z);
            bval[rr].w = f2bf(wv.w);
        }
        __syncthreads();
#pragma unroll
        for (int rr = 0; rr < 4; ++rr) {
            const int row = srow + rr * 32;
            *(ushort4*)&As[row * 32 + scol] = aval[rr];
            *(ushort4*)&Bs[row * 32 + scol] = bval[rr];
        }
        __syncthreads();

        const bf16x8* AsV = (const bf16x8*)As;
        const bf16x8* BsV = (const bf16x8*)Bs;
        bf16x8 a[4], b[4];
#pragma unroll
        for (int t = 0; t < 4; ++t) a[t] = AsV[(wm * 64 + t * 16 + mr) * 4 + quad];
#pragma unroll
        for (int t = 0; t < 4; ++t) b[t] = BsV[(wn * 64 + t * 16 + mr) * 4 + quad];
#pragma unroll
        for (int i = 0; i < 4; ++i)
#pragma unroll
            for (int jj = 0; jj < 4; ++jj)
                acc[i][jj] = __builtin_amdgcn_mfma_f32_16x16x32_bf16(a[i], b[jj], acc[i][jj], 0, 0, 0);
    }
    write_epilogue(acc, mmap, nmap, lane, wm, wn, mBase, nBase, bias2, out);
}

// ---------------- launch ----------------

extern "C" void kernel_launch(void* const* d_in, const int* in_sizes, int n_in,
                              void* d_out, int out_size, void* d_ws, size_t ws_size,
                              hipStream_t stream)
{
    (void)out_size;
    const void* x    = d_in[0];
    const void* W    = d_in[1];
    const void* C    = d_in[2];
    const void* bias = d_in[3];
    for (int i = 0; i < n_in; ++i) {
        if      (in_sizes[i] == BATCH * IN_F)     x    = d_in[i];
        else if (in_sizes[i] == OUT_F * IN_F)     W    = d_in[i];
        else if (in_sizes[i] == OUT_F * IN_F * 6) C    = d_in[i];
        else if (in_sizes[i] == OUT_F)            bias = d_in[i];
    }
    float* out = (float*)d_out;   // OUTPUT IS FP32 (round 2-4 post-mortem)
    char* ws = (char*)d_ws;

    if (ws_size >= NEEDED_BIG) {
        __hip_bfloat16* Waug  = (__hip_bfloat16*)ws;
        float*          bias2 = (float*)(ws + BIAS2_OFF);
        __hip_bfloat16* Aaug  = (__hip_bfloat16*)(ws + AAUG_OFF);
        int*            flags = (int*)(ws + FLAGS_OFF);
        int*            mmap  = (int*)(ws + MMAP_OFF);
        int*            nmap  = (int*)(ws + NMAP_OFF);
        detect_dtype<<<dim3(4),     dim3(256), 0, stream>>>(x, W, C, bias, flags);
        probe_layout<<<dim3(1),     dim3(64),  0, stream>>>(mmap, nmap);
        prep_bias   <<<dim3(OUT_F), dim3(256), 0, stream>>>(C, bias, bias2, flags);
        prep_weights<<<dim3((OUT_F * IN_F) / 256), dim3(256), 0, stream>>>(W, C, Waug, flags);
        prep_acts   <<<dim3((BATCH * IN_F) / 256), dim3(256), 0, stream>>>(x, Aaug, flags);
        gemm_kan    <<<dim3(OUT_F / 128, BATCH / 128), dim3(256), 0, stream>>>(
            Aaug, Waug, bias2, mmap, nmap, out);
    } else {
        int*   flags = (int*)(ws + S_FLAGS);
        int*   mmap  = (int*)(ws + S_MMAP);
        int*   nmap  = (int*)(ws + S_NMAP);
        float* bias2 = (float*)(ws + S_BIAS2);
        detect_dtype<<<dim3(4),     dim3(256), 0, stream>>>(x, W, C, bias, flags);
        probe_layout<<<dim3(1),     dim3(64),  0, stream>>>(mmap, nmap);
        prep_bias   <<<dim3(OUT_F), dim3(256), 0, stream>>>(C, bias, bias2, flags);
        gemm_direct <<<dim3(OUT_F / 128, BATCH / 128), dim3(256), 0, stream>>>(
            x, W, C, bias2, flags, mmap, nmap, out);
    }
}

// Round 6
// 273.417 us; speedup vs baseline: 1.0785x; 1.0785x over previous
//
#include <hip/hip_runtime.h>
#include <hip/hip_bf16.h>
#include <cstdint>
#include <cstddef>

// JacobiKANLinear: DEGREE=5, A=B=1.0
#define BATCH   8192
#define IN_F    1024
#define OUT_F   1024
#define KAUG    (6 * 1024)   // slab 0 = silu(x); slab j (1..5) = P_j(tanh x); P0 folded into bias

typedef __bf16 bf16x8 __attribute__((ext_vector_type(8)));
typedef float  f32x4  __attribute__((ext_vector_type(4)));

// Big-workspace layout (fast path, needs ~113.3 MB):
static constexpr size_t WAUG_B    = (size_t)OUT_F * KAUG * 2;        // 12,582,912
static constexpr size_t BIAS2_OFF = WAUG_B;                          // 4 KB f32
static constexpr size_t AAUG_OFF  = WAUG_B + 4096;
static constexpr size_t AAUG_B    = (size_t)BATCH * KAUG * 2;        // 100,663,296
static constexpr size_t FLAGS_OFF = AAUG_OFF + AAUG_B;
static constexpr size_t MMAP_OFF  = FLAGS_OFF + 64;
static constexpr size_t NMAP_OFF  = MMAP_OFF + 1024;
static constexpr size_t NEEDED_BIG = NMAP_OFF + 1024;
// Small-workspace layout (direct fallback, needs 8 KB):
static constexpr size_t S_FLAGS = 0, S_MMAP = 128, S_NMAP = 1152, S_BIAS2 = 4096;

// Jacobi recurrence for A=B=1 (beta_n = 0): P_k = (a_k t)P_{k-1} - (b_k)P_{k-2}
__device__ __constant__ float JAC_A[4] = {64.f/120.f, 180.f/336.f, 384.f/720.f, 700.f/1320.f};
__device__ __constant__ float JAC_B[4] = {48.f/120.f, 144.f/336.f, 320.f/720.f, 600.f/1320.f};

// ---------------- dtype detection (per input; 1 = fp32, 0 = bf16) ----------------
__global__ void detect_dtype(const void* p0, const void* p1,
                             const void* p2, const void* p3,
                             int* __restrict__ flags)
{
    const void* ps[4] = {p0, p1, p2, p3};
    const __hip_bfloat16* b = (const __hip_bfloat16*)ps[blockIdx.x];
    const float v = __bfloat162float(b[threadIdx.x]);
    const bool bad = (!(v == v)) || (fabsf(v) > 1000.f);
    const unsigned long long m = __ballot(bad);
    __shared__ int s[4];
    if ((threadIdx.x & 63) == 0) s[threadIdx.x >> 6] = (m != 0ull) ? 1 : 0;
    __syncthreads();
    if (threadIdx.x == 0) flags[blockIdx.x] = s[0] | s[1] | s[2] | s[3];
}

__device__ __forceinline__ float load_in(const void* p, size_t idx, int isf32)
{
    if (isf32) return ((const float*)p)[idx];
    const unsigned short u = ((const unsigned short*)p)[idx];
    return __uint_as_float((unsigned)u << 16);
}

__device__ __forceinline__ float4 load4(const void* p, size_t idx, int isf32)
{
    if (isf32) return *(const float4*)((const float*)p + idx);
    const ushort4 u = *(const ushort4*)((const unsigned short*)p + idx);
    float4 r;
    r.x = __uint_as_float((unsigned)u.x << 16);
    r.y = __uint_as_float((unsigned)u.y << 16);
    r.z = __uint_as_float((unsigned)u.z << 16);
    r.w = __uint_as_float((unsigned)u.w << 16);
    return r;
}

__device__ __forceinline__ unsigned short f2bf(float f)
{
    __hip_bfloat16 h = __float2bfloat16(f);
    return *(unsigned short*)&h;
}

__device__ __forceinline__ float fast_tanh(float x)
{
    const float xc = fminf(fmaxf(x, -15.f), 15.f);
    const float e  = __expf(2.f * xc);
    return (e - 1.f) / (e + 1.f);
}

__device__ __forceinline__ float slabf(float xv, int j)
{
    if (j == 0) return xv / (1.f + __expf(-xv));        // silu
    const float t = fast_tanh(xv);
    float pm2 = 1.f, pm1 = 2.f * t;                     // P1 = 2t
    if (j == 1) return pm1;
    float pk = pm1;
#pragma unroll
    for (int k = 2; k <= 5; ++k) {
        if (k > j) break;
        pk = JAC_A[k - 2] * t * pm1 - JAC_B[k - 2] * pm2;
        pm2 = pm1; pm1 = pk;
    }
    return pk;
}

// ---------------- MFMA C/D layout probe ----------------
__global__ void probe_layout(int* __restrict__ mmap, int* __restrict__ nmap)
{
    __shared__ __align__(16) __hip_bfloat16 A1[16 * 32], B1[16 * 32];
    __shared__ __align__(16) __hip_bfloat16 A2[16 * 32], B2[16 * 32];
    const int lane = threadIdx.x;
    for (int e = lane; e < 512; e += 64) {
        const int m = e >> 5, k = e & 31;
        A1[e] = __float2bfloat16((k == 0) ? (float)(m + 1) : 0.f);
        B1[e] = __float2bfloat16((k == 0) ? 1.f : 0.f);
        A2[e] = __float2bfloat16((k == 0) ? 1.f : 0.f);
        B2[e] = __float2bfloat16((k == 0) ? (float)(m + 1) : 0.f);
    }
    __syncthreads();
    const int quad = lane >> 4, mr = lane & 15;
    const int fi = mr * 4 + quad;
    const bf16x8* A1v = (const bf16x8*)A1;
    const bf16x8* B1v = (const bf16x8*)B1;
    const bf16x8* A2v = (const bf16x8*)A2;
    const bf16x8* B2v = (const bf16x8*)B2;
    f32x4 z = {};
    f32x4 d1 = __builtin_amdgcn_mfma_f32_16x16x32_bf16(A1v[fi], B1v[fi], z, 0, 0, 0);
    f32x4 d2 = __builtin_amdgcn_mfma_f32_16x16x32_bf16(A2v[fi], B2v[fi], z, 0, 0, 0);
#pragma unroll
    for (int r = 0; r < 4; ++r) {
        mmap[lane * 4 + r] = (int)(d1[r] + 0.5f) - 1;
        nmap[lane * 4 + r] = (int)(d2[r] + 0.5f) - 1;
    }
}

// ---------------- bias fold: bias2[o] = bias[o] + sum_i C[o][i][0] ----------------
__global__ void prep_bias(const void* __restrict__ C,
                          const void* __restrict__ bias,
                          float* __restrict__ bias2,
                          const int* __restrict__ flags)
{
    const int fC = flags[2], fB = flags[3];
    const int o = blockIdx.x;
    float s = 0.f;
    for (int i = threadIdx.x; i < IN_F; i += 256)
        s += load_in(C, ((size_t)o * IN_F + i) * 6, fC);
#pragma unroll
    for (int off = 32; off > 0; off >>= 1)
        s += __shfl_down(s, off, 64);
    __shared__ float red[4];
    if ((threadIdx.x & 63) == 0) red[threadIdx.x >> 6] = s;
    __syncthreads();
    if (threadIdx.x == 0)
        bias2[o] = load_in(bias, o, fB) + red[0] + red[1] + red[2] + red[3];
}

// ---------------- fast-path prep ----------------
__global__ void prep_weights(const void* __restrict__ W,
                             const void* __restrict__ C,
                             __hip_bfloat16* __restrict__ Waug,
                             const int* __restrict__ flags)
{
    const int fW = flags[1], fC = flags[2];
    const int idx = blockIdx.x * 256 + threadIdx.x;
    const int o = idx >> 10;
    const int i = idx & (IN_F - 1);
    const size_t wbase = (size_t)o * KAUG;
    Waug[wbase + i] = __float2bfloat16(load_in(W, idx, fW));
    const size_t cbase = (size_t)idx * 6;
#pragma unroll
    for (int j = 1; j <= 5; ++j)
        Waug[wbase + (size_t)j * IN_F + i] = __float2bfloat16(load_in(C, cbase + j, fC));
}

// 4 elements per thread: float4 x-load, ushort4 stores per slab.
__global__ void prep_acts(const void* __restrict__ X,
                          __hip_bfloat16* __restrict__ Aaug,
                          const int* __restrict__ flags)
{
    const int fX = flags[0];
    const int gid = blockIdx.x * 256 + threadIdx.x;   // 0 .. BATCH*IN_F/4-1
    const int b  = gid >> 8;                          // 256 float4 per row
    const int i4 = (gid & 255) * 4;
    const float4 xv = load4(X, (size_t)b * IN_F + i4, fX);
    const size_t base = (size_t)b * KAUG + i4;

    float sx[4] = {xv.x, xv.y, xv.z, xv.w};
    ushort4 o0, o1;
    float t[4], pm1[4], pm2[4];
    // silu
    o0.x = f2bf(sx[0] / (1.f + __expf(-sx[0])));
    o0.y = f2bf(sx[1] / (1.f + __expf(-sx[1])));
    o0.z = f2bf(sx[2] / (1.f + __expf(-sx[2])));
    o0.w = f2bf(sx[3] / (1.f + __expf(-sx[3])));
    *(ushort4*)&Aaug[base] = o0;
#pragma unroll
    for (int e = 0; e < 4; ++e) { t[e] = fast_tanh(sx[e]); pm2[e] = 1.f; pm1[e] = 2.f * t[e]; }
    o1.x = f2bf(pm1[0]); o1.y = f2bf(pm1[1]); o1.z = f2bf(pm1[2]); o1.w = f2bf(pm1[3]);
    *(ushort4*)&Aaug[base + IN_F] = o1;
#pragma unroll
    for (int k = 2; k <= 5; ++k) {
        ushort4 ok;
#pragma unroll
        for (int e = 0; e < 4; ++e) {
            const float pk = JAC_A[k - 2] * t[e] * pm1[e] - JAC_B[k - 2] * pm2[e];
            pm2[e] = pm1[e]; pm1[e] = pk;
        }
        ok.x = f2bf(pm1[0]); ok.y = f2bf(pm1[1]); ok.z = f2bf(pm1[2]); ok.w = f2bf(pm1[3]);
        *(ushort4*)&Aaug[base + (size_t)k * IN_F] = ok;
    }
}

// ---------------- shared epilogue ----------------
__device__ __forceinline__ void write_epilogue(
    f32x4 (&acc)[4][4], const int* mmap, const int* nmap,
    int lane, int wm, int wn, int mBase, int nBase,
    const float* bias2, float* out)
{
    const int4 mv = ((const int4*)mmap)[lane];
    const int4 nv = ((const int4*)nmap)[lane];
    const int mm[4] = {mv.x, mv.y, mv.z, mv.w};
    const int nn[4] = {nv.x, nv.y, nv.z, nv.w};
#pragma unroll
    for (int i = 0; i < 4; ++i) {
#pragma unroll
        for (int jj = 0; jj < 4; ++jj) {
#pragma unroll
            for (int r = 0; r < 4; ++r) {
                const int row = mBase + wm * 64 + i * 16 + mm[r];
                const int col = nBase + wn * 64 + jj * 16 + nn[r];
                out[(size_t)row * OUT_F + col] = acc[i][jj][r] + bias2[col];  // fp32 OUT
            }
        }
    }
}

// ---------------- fast GEMM (m97 structure: global_load_lds width=16) ----------------
__device__ __forceinline__ void async_load16(const void* g, void* l)
{
    __builtin_amdgcn_global_load_lds(
        (const __attribute__((address_space(1))) void*)g,
        (__attribute__((address_space(3))) void*)l,
        16, 0, 0);
}

__global__ __launch_bounds__(256, 2)
void gemm_kan(const __hip_bfloat16* __restrict__ Aaug,
              const __hip_bfloat16* __restrict__ Waug,
              const float* __restrict__ bias2,
              const int* __restrict__ mmap,
              const int* __restrict__ nmap,
              float* __restrict__ out)
{
    __shared__ __align__(16) __hip_bfloat16 As[128 * 32];
    __shared__ __align__(16) __hip_bfloat16 Bs[128 * 32];

    const int tid  = threadIdx.x;
    const int lane = tid & 63;
    const int wave = tid >> 6;
    const int wm = wave & 1, wn = wave >> 1;
    const int mBase = blockIdx.y * 128;
    const int nBase = blockIdx.x * 128;

    // staging: thread tid loads 16B; wave-uniform LDS base + lane*16 equals
    // row-major (srow, scol): As[srow*32 + scol] with srow=tid>>2, scol=(tid&3)*8
    const int srow = tid >> 2;              // 0..63
    const int scol = (tid & 3) * 8;         // 0,8,16,24
    const __hip_bfloat16* gA0 = Aaug + (size_t)(mBase + srow) * KAUG + scol;
    const __hip_bfloat16* gA1 = gA0 + (size_t)64 * KAUG;
    const __hip_bfloat16* gB0 = Waug + (size_t)(nBase + srow) * KAUG + scol;
    const __hip_bfloat16* gB1 = gB0 + (size_t)64 * KAUG;
    char* lA = (char*)As + wave * 1024;
    char* lB = (char*)Bs + wave * 1024;

    f32x4 acc[4][4] = {};
    const int quad = lane >> 4, mr = lane & 15;

    for (int k0 = 0; k0 < KAUG; k0 += 32) {
        async_load16(gA0 + k0, lA);
        async_load16(gA1 + k0, lA + 4096);
        async_load16(gB0 + k0, lB);
        async_load16(gB1 + k0, lB + 4096);
        __syncthreads();   // compiler drains vmcnt before s_barrier

        const bf16x8* AsV = (const bf16x8*)As;
        const bf16x8* BsV = (const bf16x8*)Bs;
        bf16x8 a[4], b[4];
#pragma unroll
        for (int t = 0; t < 4; ++t) a[t] = AsV[(wm * 64 + t * 16 + mr) * 4 + quad];
#pragma unroll
        for (int t = 0; t < 4; ++t) b[t] = BsV[(wn * 64 + t * 16 + mr) * 4 + quad];
#pragma unroll
        for (int i = 0; i < 4; ++i)
#pragma unroll
            for (int jj = 0; jj < 4; ++jj)
                acc[i][jj] = __builtin_amdgcn_mfma_f32_16x16x32_bf16(a[i], b[jj], acc[i][jj], 0, 0, 0);
        __syncthreads();
    }
    write_epilogue(acc, mmap, nmap, lane, wm, wn, mBase, nBase, bias2, out);
}

// ---------------- direct GEMM fallback (small workspace) ----------------
__global__ __launch_bounds__(256, 2)
void gemm_direct(const void* __restrict__ x,
                 const void* __restrict__ W,
                 const void* __restrict__ C,
                 const float* __restrict__ bias2,
                 const int* __restrict__ flags,
                 const int* __restrict__ mmap,
                 const int* __restrict__ nmap,
                 float* __restrict__ out)
{
    __shared__ __align__(16) __hip_bfloat16 As[128 * 32];
    __shared__ __align__(16) __hip_bfloat16 Bs[128 * 32];

    const int tid  = threadIdx.x;
    const int lane = tid & 63;
    const int wave = tid >> 6;
    const int wm = wave & 1, wn = wave >> 1;
    const int mBase = blockIdx.y * 128;
    const int nBase = blockIdx.x * 128;
    const int fX = flags[0], fW = flags[1], fC = flags[2];

    const int srow = tid >> 3;              // 0..31
    const int scol = (tid & 7) * 4;         // 0,4,...,28

    f32x4 acc[4][4] = {};
    const int quad = lane >> 4, mr = lane & 15;

    for (int k0 = 0; k0 < KAUG; k0 += 32) {
        const int j  = k0 >> 10;
        const int i0 = k0 & (IN_F - 1);
        ushort4 aval[4], bval[4];
#pragma unroll
        for (int rr = 0; rr < 4; ++rr) {
            const int row = srow + rr * 32;
            const float4 xv = load4(x, (size_t)(mBase + row) * IN_F + i0 + scol, fX);
            aval[rr].x = f2bf(slabf(xv.x, j));
            aval[rr].y = f2bf(slabf(xv.y, j));
            aval[rr].z = f2bf(slabf(xv.z, j));
            aval[rr].w = f2bf(slabf(xv.w, j));
            float4 wv;
            if (j == 0) {
                wv = load4(W, (size_t)(nBase + row) * IN_F + i0 + scol, fW);
            } else {
                const size_t cb = ((size_t)(nBase + row) * IN_F + i0 + scol) * 6 + j;
                wv.x = load_in(C, cb,      fC);
                wv.y = load_in(C, cb + 6,  fC);
                wv.z = load_in(C, cb + 12, fC);
                wv.w = load_in(C, cb + 18, fC);
            }
            bval[rr].x = f2bf(wv.x);
            bval[rr].y = f2bf(wv.y);
            bval[rr].z = f2bf(wv.z);
            bval[rr].w = f2bf(wv.w);
        }
        __syncthreads();
#pragma unroll
        for (int rr = 0; rr < 4; ++rr) {
            const int row = srow + rr * 32;
            *(ushort4*)&As[row * 32 + scol] = aval[rr];
            *(ushort4*)&Bs[row * 32 + scol] = bval[rr];
        }
        __syncthreads();

        const bf16x8* AsV = (const bf16x8*)As;
        const bf16x8* BsV = (const bf16x8*)Bs;
        bf16x8 a[4], b[4];
#pragma unroll
        for (int t = 0; t < 4; ++t) a[t] = AsV[(wm * 64 + t * 16 + mr) * 4 + quad];
#pragma unroll
        for (int t = 0; t < 4; ++t) b[t] = BsV[(wn * 64 + t * 16 + mr) * 4 + quad];
#pragma unroll
        for (int i = 0; i < 4; ++i)
#pragma unroll
            for (int jj = 0; jj < 4; ++jj)
                acc[i][jj] = __builtin_amdgcn_mfma_f32_16x16x32_bf16(a[i], b[jj], acc[i][jj], 0, 0, 0);
    }
    write_epilogue(acc, mmap, nmap, lane, wm, wn, mBase, nBase, bias2, out);
}

// ---------------- launch ----------------

extern "C" void kernel_launch(void* const* d_in, const int* in_sizes, int n_in,
                              void* d_out, int out_size, void* d_ws, size_t ws_size,
                              hipStream_t stream)
{
    (void)out_size;
    const void* x    = d_in[0];
    const void* W    = d_in[1];
    const void* C    = d_in[2];
    const void* bias = d_in[3];
    for (int i = 0; i < n_in; ++i) {
        if      (in_sizes[i] == BATCH * IN_F)     x    = d_in[i];
        else if (in_sizes[i] == OUT_F * IN_F)     W    = d_in[i];
        else if (in_sizes[i] == OUT_F * IN_F * 6) C    = d_in[i];
        else if (in_sizes[i] == OUT_F)            bias = d_in[i];
    }
    float* out = (float*)d_out;   // fp32 output (verified round 5)
    char* ws = (char*)d_ws;

    if (ws_size >= NEEDED_BIG) {
        __hip_bfloat16* Waug  = (__hip_bfloat16*)ws;
        float*          bias2 = (float*)(ws + BIAS2_OFF);
        __hip_bfloat16* Aaug  = (__hip_bfloat16*)(ws + AAUG_OFF);
        int*            flags = (int*)(ws + FLAGS_OFF);
        int*            mmap  = (int*)(ws + MMAP_OFF);
        int*            nmap  = (int*)(ws + NMAP_OFF);
        detect_dtype<<<dim3(4),     dim3(256), 0, stream>>>(x, W, C, bias, flags);
        probe_layout<<<dim3(1),     dim3(64),  0, stream>>>(mmap, nmap);
        prep_bias   <<<dim3(OUT_F), dim3(256), 0, stream>>>(C, bias, bias2, flags);
        prep_weights<<<dim3((OUT_F * IN_F) / 256), dim3(256), 0, stream>>>(W, C, Waug, flags);
        prep_acts   <<<dim3((BATCH * IN_F) / 1024), dim3(256), 0, stream>>>(x, Aaug, flags);
        gemm_kan    <<<dim3(OUT_F / 128, BATCH / 128), dim3(256), 0, stream>>>(
            Aaug, Waug, bias2, mmap, nmap, out);
    } else {
        int*   flags = (int*)(ws + S_FLAGS);
        int*   mmap  = (int*)(ws + S_MMAP);
        int*   nmap  = (int*)(ws + S_NMAP);
        float* bias2 = (float*)(ws + S_BIAS2);
        detect_dtype<<<dim3(4),     dim3(256), 0, stream>>>(x, W, C, bias, flags);
        probe_layout<<<dim3(1),     dim3(64),  0, stream>>>(mmap, nmap);
        prep_bias   <<<dim3(OUT_F), dim3(256), 0, stream>>>(C, bias, bias2, flags);
        gemm_direct <<<dim3(OUT_F / 128, BATCH / 128), dim3(256), 0, stream>>>(
            x, W, C, bias2, flags, mmap, nmap, out);
    }
}

// Round 7
// 250.136 us; speedup vs baseline: 1.1789x; 1.0931x over previous
//
#include <hip/hip_runtime.h>
#include <hip/hip_bf16.h>
#include <cstdint>
#include <cstddef>

// JacobiKANLinear: DEGREE=5, A=B=1.0. Inputs fp32, output fp32 (HW-verified r1/r2/r5).
#define BATCH   8192
#define IN_F    1024
#define OUT_F   1024
#define KAUG    (6 * 1024)   // slab 0 = silu(x); slab j (1..5) = P_j(tanh x); P0 folded into bias

typedef __bf16 bf16x8 __attribute__((ext_vector_type(8)));
typedef float  f32x4  __attribute__((ext_vector_type(4)));

// Workspace layout (bytes), needs ~113.3 MB (verified available in r5/r6):
static constexpr size_t WAUG_B    = (size_t)OUT_F * KAUG * 2;        // 12,582,912
static constexpr size_t BIAS2_OFF = WAUG_B;                          // 4 KB f32
static constexpr size_t AAUG_OFF  = WAUG_B + 4096;
static constexpr size_t AAUG_B    = (size_t)BATCH * KAUG * 2;        // 100,663,296
static constexpr size_t MMAP_OFF  = AAUG_OFF + AAUG_B;
static constexpr size_t NMAP_OFF  = MMAP_OFF + 1024;

// Jacobi recurrence for A=B=1 (beta_n = 0): P_k = (a_k t)P_{k-1} - (b_k)P_{k-2}
__device__ __constant__ float JAC_A[4] = {64.f/120.f, 180.f/336.f, 384.f/720.f, 700.f/1320.f};
__device__ __constant__ float JAC_B[4] = {48.f/120.f, 144.f/336.f, 320.f/720.f, 600.f/1320.f};

__device__ __forceinline__ unsigned short f2bf(float f)
{
    __hip_bfloat16 h = __float2bfloat16(f);
    return *(unsigned short*)&h;
}
__device__ __forceinline__ unsigned pack2(float lo, float hi)
{
    return (unsigned)f2bf(lo) | ((unsigned)f2bf(hi) << 16);
}
__device__ __forceinline__ float fast_tanh(float x)
{
    const float xc = fminf(fmaxf(x, -15.f), 15.f);
    const float e  = __expf(2.f * xc);
    return (e - 1.f) / (e + 1.f);
}

// ---------------- MFMA C/D layout probe (feeds epilogue; mapping-direction-proof) ----
__global__ void probe_layout(int* __restrict__ mmap, int* __restrict__ nmap)
{
    __shared__ __align__(16) __hip_bfloat16 A1[16 * 32], B1[16 * 32];
    __shared__ __align__(16) __hip_bfloat16 A2[16 * 32], B2[16 * 32];
    const int lane = threadIdx.x;
    for (int e = lane; e < 512; e += 64) {
        const int m = e >> 5, k = e & 31;
        A1[e] = __float2bfloat16((k == 0) ? (float)(m + 1) : 0.f);
        B1[e] = __float2bfloat16((k == 0) ? 1.f : 0.f);
        A2[e] = __float2bfloat16((k == 0) ? 1.f : 0.f);
        B2[e] = __float2bfloat16((k == 0) ? (float)(m + 1) : 0.f);
    }
    __syncthreads();
    const int quad = lane >> 4, mr = lane & 15;
    const int fi = mr * 4 + quad;          // same index math as gemm frag loads
    f32x4 z = {};
    f32x4 d1 = __builtin_amdgcn_mfma_f32_16x16x32_bf16(((const bf16x8*)A1)[fi], ((const bf16x8*)B1)[fi], z, 0, 0, 0);
    f32x4 d2 = __builtin_amdgcn_mfma_f32_16x16x32_bf16(((const bf16x8*)A2)[fi], ((const bf16x8*)B2)[fi], z, 0, 0, 0);
#pragma unroll
    for (int r = 0; r < 4; ++r) {
        mmap[lane * 4 + r] = (int)(d1[r] + 0.5f) - 1;
        nmap[lane * 4 + r] = (int)(d2[r] + 0.5f) - 1;
    }
}

// ---------------- fused weights + bias prep ----------------
// Block b = output row o. Thread tid owns i = tid*4..tid*4+3:
//  - W row load: float4 (coalesced)
//  - C load: 24 CONSECUTIVE floats (12 float2) — replaces the stride-6 gather
//  - writes Waug slabs as ushort4; reduces sum_i C[o,i,0] into bias2[o]
__global__ void prep_wb(const float* __restrict__ W,
                        const float* __restrict__ C,
                        const float* __restrict__ bias,
                        __hip_bfloat16* __restrict__ Waug,
                        float* __restrict__ bias2)
{
    const int o   = blockIdx.x;
    const int tid = threadIdx.x;
    const int i   = tid * 4;
    const size_t wbase = (size_t)o * KAUG;

    const float4 wv = *(const float4*)(W + (size_t)o * IN_F + i);
    ((uint2*)&Waug[wbase + i])[0] = make_uint2(pack2(wv.x, wv.y), pack2(wv.z, wv.w));

    // 24 consecutive floats: C[(o*IN_F+i)*6 .. +23] = c[e][j], e=0..3, j=0..5
    float f[24];
    const float2* cp = (const float2*)(C + ((size_t)o * IN_F + i) * 6);
#pragma unroll
    for (int q = 0; q < 12; ++q) { const float2 v = cp[q]; f[q * 2] = v.x; f[q * 2 + 1] = v.y; }

#pragma unroll
    for (int j = 1; j <= 5; ++j) {
        ((uint2*)&Waug[wbase + (size_t)j * IN_F + i])[0] =
            make_uint2(pack2(f[0 + j], f[6 + j]), pack2(f[12 + j], f[18 + j]));
    }

    float s = f[0] + f[6] + f[12] + f[18];        // j = 0 terms
#pragma unroll
    for (int off = 32; off > 0; off >>= 1) s += __shfl_down(s, off, 64);
    __shared__ float red[4];
    if ((tid & 63) == 0) red[tid >> 6] = s;
    __syncthreads();
    if (tid == 0) bias2[o] = bias[o] + red[0] + red[1] + red[2] + red[3];
}

// ---------------- activation prep: 8 elems/thread, 16B stores ----------------
__global__ void prep_acts(const float* __restrict__ X,
                          __hip_bfloat16* __restrict__ Aaug)
{
    const int gid = blockIdx.x * 256 + threadIdx.x;   // 0 .. BATCH*IN_F/8-1
    const int b   = gid >> 7;                         // 128 threads per row
    const int i8  = (gid & 127) * 8;
    const float4 x0 = *(const float4*)(X + (size_t)b * IN_F + i8);
    const float4 x1 = *(const float4*)(X + (size_t)b * IN_F + i8 + 4);
    const float sx[8] = {x0.x, x0.y, x0.z, x0.w, x1.x, x1.y, x1.z, x1.w};
    const size_t base = (size_t)b * KAUG + i8;

    float sil[8], t[8], pm1[8], pm2[8];
#pragma unroll
    for (int e = 0; e < 8; ++e) {
        sil[e] = sx[e] / (1.f + __expf(-sx[e]));
        t[e]   = fast_tanh(sx[e]);
        pm2[e] = 1.f; pm1[e] = 2.f * t[e];            // P1 = 2t
    }
    *(uint4*)&Aaug[base] = make_uint4(pack2(sil[0], sil[1]), pack2(sil[2], sil[3]),
                                      pack2(sil[4], sil[5]), pack2(sil[6], sil[7]));
    *(uint4*)&Aaug[base + IN_F] = make_uint4(pack2(pm1[0], pm1[1]), pack2(pm1[2], pm1[3]),
                                             pack2(pm1[4], pm1[5]), pack2(pm1[6], pm1[7]));
#pragma unroll
    for (int k = 2; k <= 5; ++k) {
#pragma unroll
        for (int e = 0; e < 8; ++e) {
            const float pk = JAC_A[k - 2] * t[e] * pm1[e] - JAC_B[k - 2] * pm2[e];
            pm2[e] = pm1[e]; pm1[e] = pk;
        }
        *(uint4*)&Aaug[base + (size_t)k * IN_F] =
            make_uint4(pack2(pm1[0], pm1[1]), pack2(pm1[2], pm1[3]),
                       pack2(pm1[4], pm1[5]), pack2(pm1[6], pm1[7]));
    }
}

// ---------------- GEMM: 128x128 tile, K unrolled 2x32 into separate LDS buffers ----
__device__ __forceinline__ void async_load16(const void* g, void* l)
{
    __builtin_amdgcn_global_load_lds(
        (const __attribute__((address_space(1))) void*)g,
        (__attribute__((address_space(3))) void*)l,
        16, 0, 0);
}

__global__ __launch_bounds__(256, 2)
void gemm_kan(const __hip_bfloat16* __restrict__ Aaug,
              const __hip_bfloat16* __restrict__ Waug,
              const float* __restrict__ bias2,
              const int* __restrict__ mmap,
              const int* __restrict__ nmap,
              float* __restrict__ out)
{
    // four proven-layout 128x32 buffers (row-major, 64B row stride) = 32 KB
    __shared__ __align__(16) __hip_bfloat16 As[128 * 32], Bs[128 * 32];
    __shared__ __align__(16) __hip_bfloat16 As2[128 * 32], Bs2[128 * 32];

    const int tid  = threadIdx.x;
    const int lane = tid & 63;
    const int wave = tid >> 6;
    const int wm = wave & 1, wn = wave >> 1;
    const int mBase = blockIdx.y * 128;
    const int nBase = blockIdx.x * 128;

    const int srow = tid >> 2;              // 0..63
    const int scol = (tid & 3) * 8;         // 0,8,16,24
    const __hip_bfloat16* gA0 = Aaug + (size_t)(mBase + srow) * KAUG + scol;
    const __hip_bfloat16* gA1 = gA0 + (size_t)64 * KAUG;
    const __hip_bfloat16* gB0 = Waug + (size_t)(nBase + srow) * KAUG + scol;
    const __hip_bfloat16* gB1 = gB0 + (size_t)64 * KAUG;
    char* lA  = (char*)As  + wave * 1024;
    char* lB  = (char*)Bs  + wave * 1024;
    char* lA2 = (char*)As2 + wave * 1024;
    char* lB2 = (char*)Bs2 + wave * 1024;

    f32x4 acc[4][4] = {};
    const int quad = lane >> 4, mr = lane & 15;
    const int fbase = mr * 4 + quad;        // frag index within a 16-row group

    for (int k0 = 0; k0 < KAUG; k0 += 64) {
        async_load16(gA0 + k0, lA);
        async_load16(gA1 + k0, lA + 4096);
        async_load16(gB0 + k0, lB);
        async_load16(gB1 + k0, lB + 4096);
        async_load16(gA0 + k0 + 32, lA2);
        async_load16(gA1 + k0 + 32, lA2 + 4096);
        async_load16(gB0 + k0 + 32, lB2);
        async_load16(gB1 + k0 + 32, lB2 + 4096);
        __syncthreads();   // drains all 8 async loads

        // chunk 0
        {
            const bf16x8* AsV = (const bf16x8*)As;
            const bf16x8* BsV = (const bf16x8*)Bs;
            bf16x8 a[4], b[4];
#pragma unroll
            for (int t = 0; t < 4; ++t) a[t] = AsV[(wm * 64 + t * 16) * 4 + fbase];
#pragma unroll
            for (int t = 0; t < 4; ++t) b[t] = BsV[(wn * 64 + t * 16) * 4 + fbase];
#pragma unroll
            for (int i = 0; i < 4; ++i)
#pragma unroll
                for (int jj = 0; jj < 4; ++jj)
                    acc[i][jj] = __builtin_amdgcn_mfma_f32_16x16x32_bf16(a[i], b[jj], acc[i][jj], 0, 0, 0);
        }
        // chunk 1
        {
            const bf16x8* AsV = (const bf16x8*)As2;
            const bf16x8* BsV = (const bf16x8*)Bs2;
            bf16x8 a[4], b[4];
#pragma unroll
            for (int t = 0; t < 4; ++t) a[t] = AsV[(wm * 64 + t * 16) * 4 + fbase];
#pragma unroll
            for (int t = 0; t < 4; ++t) b[t] = BsV[(wn * 64 + t * 16) * 4 + fbase];
#pragma unroll
            for (int i = 0; i < 4; ++i)
#pragma unroll
                for (int jj = 0; jj < 4; ++jj)
                    acc[i][jj] = __builtin_amdgcn_mfma_f32_16x16x32_bf16(a[i], b[jj], acc[i][jj], 0, 0, 0);
        }
        __syncthreads();
    }

    // Epilogue via measured C/D maps
    const int4 mv = ((const int4*)mmap)[lane];
    const int4 nv = ((const int4*)nmap)[lane];
    const int mm[4] = {mv.x, mv.y, mv.z, mv.w};
    const int nn[4] = {nv.x, nv.y, nv.z, nv.w};
#pragma unroll
    for (int i = 0; i < 4; ++i) {
#pragma unroll
        for (int jj = 0; jj < 4; ++jj) {
#pragma unroll
            for (int r = 0; r < 4; ++r) {
                const int row = mBase + wm * 64 + i * 16 + mm[r];
                const int col = nBase + wn * 64 + jj * 16 + nn[r];
                out[(size_t)row * OUT_F + col] = acc[i][jj][r] + bias2[col];
            }
        }
    }
}

// ---------------- launch ----------------

extern "C" void kernel_launch(void* const* d_in, const int* in_sizes, int n_in,
                              void* d_out, int out_size, void* d_ws, size_t ws_size,
                              hipStream_t stream)
{
    (void)out_size; (void)ws_size;
    const float* x    = (const float*)d_in[0];
    const float* W    = (const float*)d_in[1];
    const float* C    = (const float*)d_in[2];
    const float* bias = (const float*)d_in[3];
    for (int i = 0; i < n_in; ++i) {
        if      (in_sizes[i] == BATCH * IN_F)     x    = (const float*)d_in[i];
        else if (in_sizes[i] == OUT_F * IN_F)     W    = (const float*)d_in[i];
        else if (in_sizes[i] == OUT_F * IN_F * 6) C    = (const float*)d_in[i];
        else if (in_sizes[i] == OUT_F)            bias = (const float*)d_in[i];
    }
    float* out = (float*)d_out;
    char* ws = (char*)d_ws;
    __hip_bfloat16* Waug  = (__hip_bfloat16*)ws;
    float*          bias2 = (float*)(ws + BIAS2_OFF);
    __hip_bfloat16* Aaug  = (__hip_bfloat16*)(ws + AAUG_OFF);
    int*            mmap  = (int*)(ws + MMAP_OFF);
    int*            nmap  = (int*)(ws + NMAP_OFF);

    probe_layout<<<dim3(1),     dim3(64),  0, stream>>>(mmap, nmap);
    prep_wb     <<<dim3(OUT_F), dim3(256), 0, stream>>>(W, C, bias, Waug, bias2);
    prep_acts   <<<dim3((BATCH * IN_F) / 2048), dim3(256), 0, stream>>>(x, Aaug);
    gemm_kan    <<<dim3(OUT_F / 128, BATCH / 128), dim3(256), 0, stream>>>(
        Aaug, Waug, bias2, mmap, nmap, out);
}